// Round 16
// baseline (16816.220 us; speedup 1.0000x reference)
//
#include <hip/hip_runtime.h>
#include <hip/hip_bf16.h>
#include <stdint.h>

#define T_STEPS 512
#define NBATCH 64
#define HID 1024
#define NGATE 4096
#define NLAYERS 2
#define BH (NBATCH * HID)            // 65536
#define TBH (T_STEPS * NBATCH * HID) // 33554432
#define WEL ((size_t)NLAYERS * NGATE * HID)
#define GBLK 128                     // blocks per barrier group

typedef __attribute__((ext_vector_type(8))) short short8;
typedef __attribute__((ext_vector_type(4))) float f32x4;

__device__ __forceinline__ ushort f2bf(float f) {
  union { float f; uint32_t i; } u; u.f = f;
  return (ushort)((u.i + 0x7fffu + ((u.i >> 16) & 1u)) >> 16);  // RNE
}
__device__ __forceinline__ void gll16(const void* g, void* l) {
  __builtin_amdgcn_global_load_lds(
      (const __attribute__((address_space(1))) unsigned int*)g,
      (__attribute__((address_space(3))) unsigned int*)l, 16, 0, 0);
}

// MODE ablation levels (attribution round):
//  0 = sync skeleton only (gates + arrives + dummy h-store/load-back)
//  1 = + A-load pipe (counted vmcnt; loads kept live, not consumed)
//  2 = + MFMA + B-LDS reads (acc sunk; no transpose/epilogue/out)
//  3 = FULL (real output; byte-identical math to r13)
template<int MODE>
__device__ __forceinline__ void conStep(const short8& a, const char* bb0, const char* bb1,
                                        int kc, int kb, int bsw, f32x4& accA, f32x4& accB) {
  if constexpr (MODE >= 2) {
    const short8 b0v = *(const short8*)(bb0 + ((kc * 64 + kb) ^ bsw));
    const short8 b1v = *(const short8*)(bb1 + ((kc * 64 + kb) ^ bsw));
    accA = __builtin_amdgcn_mfma_f32_16x16x32_bf16(a, b0v, accA, 0, 0, 0);
    accB = __builtin_amdgcn_mfma_f32_16x16x32_bf16(a, b1v, accB, 0, 0, 0);
  } else {
    asm volatile("" :: "v"(a));  // keep load live without consuming (rule 17)
  }
}

#define ISSC(S, P, OFF) \
  asm volatile("global_load_dwordx4 %0, %1, off offset:" #OFF \
               : "=v"(fr[S]) : "v"(P));
#define VMW(N, SLOT) \
  asm volatile("s_waitcnt vmcnt(" #N ")" : "+v"(fr[SLOT]));
#define CON(SLOT, KC) conStep<MODE>(fr[SLOT], bb0, bb1, (KC), kb, bsw, accA, accB);

// One K=1024 half (r13-proven): issue 16, interleave, countdown.
#define PIPE32(Pp, KB) \
  ISSC(0,Pp,0)    ISSC(1,Pp,64)   ISSC(2,Pp,128)  ISSC(3,Pp,192)  \
  ISSC(4,Pp,256)  ISSC(5,Pp,320)  ISSC(6,Pp,384)  ISSC(7,Pp,448)  \
  ISSC(8,Pp,512)  ISSC(9,Pp,576)  ISSC(10,Pp,640) ISSC(11,Pp,704) \
  ISSC(12,Pp,768) ISSC(13,Pp,832) ISSC(14,Pp,896) ISSC(15,Pp,960) \
  VMW(15,0)  CON(0,(KB)+0)   ISSC(0,Pp,1024)  \
  VMW(15,1)  CON(1,(KB)+1)   ISSC(1,Pp,1088)  \
  VMW(15,2)  CON(2,(KB)+2)   ISSC(2,Pp,1152)  \
  VMW(15,3)  CON(3,(KB)+3)   ISSC(3,Pp,1216)  \
  VMW(15,4)  CON(4,(KB)+4)   ISSC(4,Pp,1280)  \
  VMW(15,5)  CON(5,(KB)+5)   ISSC(5,Pp,1344)  \
  VMW(15,6)  CON(6,(KB)+6)   ISSC(6,Pp,1408)  \
  VMW(15,7)  CON(7,(KB)+7)   ISSC(7,Pp,1472)  \
  VMW(15,8)  CON(8,(KB)+8)   ISSC(8,Pp,1536)  \
  VMW(15,9)  CON(9,(KB)+9)   ISSC(9,Pp,1600)  \
  VMW(15,10) CON(10,(KB)+10) ISSC(10,Pp,1664) \
  VMW(15,11) CON(11,(KB)+11) ISSC(11,Pp,1728) \
  VMW(15,12) CON(12,(KB)+12) ISSC(12,Pp,1792) \
  VMW(15,13) CON(13,(KB)+13) ISSC(13,Pp,1856) \
  VMW(15,14) CON(14,(KB)+14) ISSC(14,Pp,1920) \
  VMW(15,15) CON(15,(KB)+15) ISSC(15,Pp,1984) \
  VMW(15,0)  CON(0,(KB)+16)  \
  VMW(14,1)  CON(1,(KB)+17)  \
  VMW(13,2)  CON(2,(KB)+18)  \
  VMW(12,3)  CON(3,(KB)+19)  \
  VMW(11,4)  CON(4,(KB)+20)  \
  VMW(10,5)  CON(5,(KB)+21)  \
  VMW(9,6)   CON(6,(KB)+22)  \
  VMW(8,7)   CON(7,(KB)+23)  \
  VMW(7,8)   CON(8,(KB)+24)  \
  VMW(6,9)   CON(9,(KB)+25)  \
  VMW(5,10)  CON(10,(KB)+26) \
  VMW(4,11)  CON(11,(KB)+27) \
  VMW(3,12)  CON(12,(KB)+28) \
  VMW(2,13)  CON(13,(KB)+29) \
  VMW(1,14)  CON(14,(KB)+30) \
  VMW(0,15)  CON(15,(KB)+31)

// ---------------- elementwise helpers ----------------
__global__ void k_f32_to_bf16(const float* __restrict__ in, ushort* __restrict__ out, int n) {
  int i = (blockIdx.x * blockDim.x + threadIdx.x) * 4;
  if (i >= n) return;
  const float4 v = *reinterpret_cast<const float4*>(in + i);
  ushort4 o; o.x = f2bf(v.x); o.y = f2bf(v.y); o.z = f2bf(v.z); o.w = f2bf(v.w);
  *reinterpret_cast<ushort4*>(out + i) = o;
}
__global__ void k_zero(int* p, int n) {
  int i = blockIdx.x * blockDim.x + threadIdx.x;
  if (i < n) p[i] = 0;
}

// ---------------- persistent fused scan (r13 structure) ----------------
struct ScanP {
  const ushort* wih; const ushort* whh;
  const ushort* xb;  const ushort* hinit;
  ushort* h0r;                            // layer-0 h ring (T_STEPS slots)
  ushort* h1r;                            // layer-1 h ring (T_STEPS slots)
  const float* c0; const float* bi; const float* bh;
  float* out; int* bar;
};

__device__ __forceinline__ void garrive(int* gb, int stripe) {
  __syncthreads();
  if (threadIdx.x == 0)
    __hip_atomic_fetch_add(gb + stripe * 16, 1, __ATOMIC_RELAXED, __HIP_MEMORY_SCOPE_AGENT);
}
__device__ __forceinline__ void gwait(int* gb, int target, bool isRoot) {
  if (threadIdx.x == 0) {
    if (isRoot) {
      const int need = target * GBLK;
      for (;;) {
        int sum = 0;
#pragma unroll
        for (int i = 0; i < 16; ++i)
          sum += __hip_atomic_load(gb + i * 16, __ATOMIC_RELAXED, __HIP_MEMORY_SCOPE_AGENT);
        if (sum >= need) break;
        __builtin_amdgcn_s_sleep(1);
      }
      __hip_atomic_store(gb + 256, target, __ATOMIC_RELAXED, __HIP_MEMORY_SCOPE_AGENT);
    } else {
      while (__hip_atomic_load(gb + 256, __ATOMIC_RELAXED, __HIP_MEMORY_SCOPE_AGENT) < target)
        __builtin_amdgcn_s_sleep(2);
    }
  }
  __syncthreads();
  __builtin_amdgcn_sched_barrier(0);
}

template<int MODE>
__global__ __launch_bounds__(256, 1) void k_scan(ScanP p) {
  __shared__ __align__(16) ushort Wl[32 * 2048];  // 128 KB
  __shared__ float glds[64 * 33];
  const int tid = threadIdx.x, wave = tid >> 6, lane = tid & 63;
  const bool isL1 = blockIdx.x >= 128;
  const int cb = isL1 ? (int)blockIdx.x - 128 : (int)blockIdx.x;
  const int j0 = cb * 8;
  const int stripe = cb & 15;
  const bool isRoot = (cb == 0);
  int* gb = p.bar + (isL1 ? 512 : 0);
  const int* rel0 = p.bar + 256;

  if constexpr (MODE >= 2) {
    const ushort* wihL = p.wih + (isL1 ? (size_t)NGATE * HID : 0);
    const ushort* whhL = p.whh + (isL1 ? (size_t)NGATE * HID : 0);
    for (int q = wave; q < 128; q += 4) {
      const int i = q >> 2, ch = q & 3;
      const ushort* base = (ch < 2) ? wihL : whhL;
      const int g = (i >> 3) * 1024 + j0 + (i & 7);
      gll16(base + (size_t)g * 1024 + (ch & 1) * 512 + (((lane * 16) ^ ((i & 7) << 4)) >> 1),
            (char*)Wl + i * 4096 + ch * 1024);
    }
  }

  const int eb  = tid >> 2;
  const int jl0 = (tid & 3) * 2;
  const int jj  = j0 + jl0;
  const int lofs = isL1 ? NGATE : 0;
  float creg[2] = {0.f, 0.f}, bias[4][2];
  if constexpr (MODE == 3) {
#pragma unroll
    for (int i = 0; i < 2; ++i) creg[i] = p.c0[(isL1 ? BH : 0) + eb * 1024 + jj + i];
#pragma unroll
    for (int g = 0; g < 4; ++g)
#pragma unroll
      for (int i = 0; i < 2; ++i)
        bias[g][i] = p.bi[lofs + g * 1024 + jj + i] + p.bh[lofs + g * 1024 + jj + i];
  }

  const size_t aoff = (size_t)(wave * 16 + (lane & 15)) * 1024 + (size_t)((lane >> 4) * 8);
  const int r0 = lane & 15;
  const char* bb0 = (const char*)Wl + r0 * 4096;
  const char* bb1 = (const char*)Wl + (r0 + 16) * 4096;
  const int bsw = (r0 & 7) << 4;
  const int kb = (lane >> 4) * 16;

  int seen0 = 0;

  __syncthreads();  // W staged

  for (int t = 0; t < T_STEPS; ++t) {
    f32x4 accA = {0.f, 0.f, 0.f, 0.f}, accB = {0.f, 0.f, 0.f, 0.f};
    short8 fr[16];

    if (!isL1) {
      if constexpr (MODE >= 1) {
        const ushort* Pp = p.xb + (size_t)t * BH + aoff;          // EARLY: x_t
        PIPE32(Pp, 0)
      }
      if (t > 0) gwait(gb, t, isRoot);
      if constexpr (MODE >= 1) {
        const ushort* Qp = ((t == 0) ? p.hinit
                                     : p.h0r + (size_t)(t - 1) * BH) + aoff;
        PIPE32(Qp, 32)                                            // LATE: h0[t-1]
      }
    } else {
      if (threadIdx.x == 0 && seen0 < t + 1) {                    // gate: h0[t]
        int v = __hip_atomic_load(rel0, __ATOMIC_RELAXED, __HIP_MEMORY_SCOPE_AGENT);
        while (v < t + 1) {
          __builtin_amdgcn_s_sleep(2);
          v = __hip_atomic_load(rel0, __ATOMIC_RELAXED, __HIP_MEMORY_SCOPE_AGENT);
        }
        seen0 = v;
      }
      __syncthreads();
      __builtin_amdgcn_sched_barrier(0);
      if constexpr (MODE >= 1) {
        const ushort* Pp = p.h0r + (size_t)t * BH + aoff;         // EARLY: h0[t]
        PIPE32(Pp, 0)
      }
      if (t > 0) gwait(gb, t, isRoot);
      if constexpr (MODE >= 1) {
        const ushort* Qp = ((t == 0) ? p.hinit + BH
                                     : p.h1r + (size_t)(t - 1) * BH) + aoff;
        PIPE32(Qp, 32)                                            // LATE: h1[t-1]
      }
    }

    ushort* hdst = (!isL1) ? (p.h0r + (size_t)t * BH) : (p.h1r + (size_t)t * BH);
    uint32_t* hw = (uint32_t*)(hdst + eb * 1024 + jj);

    if constexpr (MODE == 3) {
#pragma unroll
      for (int r = 0; r < 4; ++r) {
        const int row = wave * 16 + (lane >> 4) * 4 + r;
        glds[row * 33 + r0]      = accA[r];
        glds[row * 33 + 16 + r0] = accB[r];
      }
      __syncthreads();

      float hres[2];
#pragma unroll
      for (int i = 0; i < 2; ++i) {
        const int jl = jl0 + i;
        const float gi = glds[eb * 33 + jl]      + bias[0][i];
        const float gf = glds[eb * 33 + 8 + jl]  + bias[1][i];
        const float gg = glds[eb * 33 + 16 + jl] + bias[2][i];
        const float go = glds[eb * 33 + 24 + jl] + bias[3][i];
        float c = creg[i];
        const float si = 1.f / (1.f + __expf(-gi));
        const float sf = 1.f / (1.f + __expf(-gf));
        const float so = 1.f / (1.f + __expf(-go));
        const float tg = tanhf(gg);
        c = sf * c + si * tg;
        hres[i] = so * tanhf(c);
        creg[i] = c;
      }

      const uint32_t packed = (uint32_t)f2bf(hres[0]) | ((uint32_t)f2bf(hres[1]) << 16);
      __hip_atomic_store(hw, packed, __ATOMIC_RELAXED, __HIP_MEMORY_SCOPE_AGENT);
      uint32_t chk = __hip_atomic_load(hw, __ATOMIC_RELAXED, __HIP_MEMORY_SCOPE_AGENT);
      asm volatile("" :: "v"(chk));

      if (isL1) {
#pragma unroll
        for (int i = 0; i < 2; ++i)
          p.out[(size_t)t * BH + eb * 1024 + jj + i] = hres[i];
        if (t == T_STEPS - 1) {
#pragma unroll
          for (int i = 0; i < 2; ++i) {
            p.out[(size_t)TBH + BH + eb * 1024 + jj + i] = hres[i];
            p.out[(size_t)TBH + 3 * BH + eb * 1024 + jj + i] = creg[i];
          }
        }
      } else if (t == T_STEPS - 1) {
#pragma unroll
        for (int i = 0; i < 2; ++i) {
          p.out[(size_t)TBH + eb * 1024 + jj + i] = hres[i];
          p.out[(size_t)TBH + 2 * BH + eb * 1024 + jj + i] = creg[i];
        }
      }
    } else {
      if constexpr (MODE == 2) asm volatile("" :: "v"(accA), "v"(accB));  // keep MFMAs live
      // dummy h-store + load-back: identical sync/transport path, constant value
      __hip_atomic_store(hw, 0x3f803f80u, __ATOMIC_RELAXED, __HIP_MEMORY_SCOPE_AGENT);
      uint32_t chk = __hip_atomic_load(hw, __ATOMIC_RELAXED, __HIP_MEMORY_SCOPE_AGENT);
      asm volatile("" :: "v"(chk));
    }

    garrive(gb, stripe);
  }

  // tail publisher (L1 steps 510/511 need rel0 beyond in-loop publish)
  if (!isL1 && isRoot && threadIdx.x == 0) {
    const int need = T_STEPS * GBLK;
    for (;;) {
      int sum = 0;
#pragma unroll
      for (int i = 0; i < 16; ++i)
        sum += __hip_atomic_load(gb + i * 16, __ATOMIC_RELAXED, __HIP_MEMORY_SCOPE_AGENT);
      if (sum >= need) break;
      __builtin_amdgcn_s_sleep(1);
    }
    __hip_atomic_store(gb + 256, T_STEPS + 1, __ATOMIC_RELAXED, __HIP_MEMORY_SCOPE_AGENT);
  }
}

// ---------------- host ----------------
extern "C" void kernel_launch(void* const* d_in, const int* in_sizes, int n_in,
                              void* d_out, int out_size, void* d_ws, size_t ws_size,
                              hipStream_t stream) {
  const float* x    = (const float*)d_in[0];
  const float* h0   = (const float*)d_in[1];
  const float* c0   = (const float*)d_in[2];
  const float* w_ih = (const float*)d_in[3];
  const float* w_hh = (const float*)d_in[4];
  const float* b_ih = (const float*)d_in[5];
  const float* b_hh = (const float*)d_in[6];
  float* out = (float*)d_out;

  ushort* xb    = (ushort*)d_ws;
  ushort* wihb  = xb + (size_t)TBH;
  ushort* whhb  = wihb + WEL;
  ushort* hinit = whhb + WEL;
  ushort* h0r   = hinit + 2 * (size_t)BH;            // ring: T_STEPS slots
  ushort* h1r   = h0r + (size_t)TBH;                 // ring: T_STEPS slots
  int*    bar   = (int*)(h1r + (size_t)TBH);         // 4 regions x 1024 ints

  const size_t need = ((size_t)3 * TBH + 2 * WEL + 2 * (size_t)BH) * 2 + 32768;
  if (ws_size < need) return;  // loud failure: d_out stays poisoned

  { int n = TBH;        k_f32_to_bf16<<<(n / 4 + 255) / 256, 256, 0, stream>>>(x, xb, n); }
  { int n = (int)WEL;   k_f32_to_bf16<<<(n / 4 + 255) / 256, 256, 0, stream>>>(w_ih, wihb, n); }
  { int n = (int)WEL;   k_f32_to_bf16<<<(n / 4 + 255) / 256, 256, 0, stream>>>(w_hh, whhb, n); }
  { int n = 2 * BH;     k_f32_to_bf16<<<(n / 4 + 255) / 256, 256, 0, stream>>>(h0, hinit, n); }
  k_zero<<<16, 256, 0, stream>>>(bar, 4096);

  ScanP sp;
  sp.wih = wihb; sp.whh = whhb;
  sp.xb = xb; sp.hinit = hinit;
  sp.h0r = h0r; sp.h1r = h1r;
  sp.c0 = c0; sp.bi = b_ih; sp.bh = b_hh;
  sp.out = out;

  // Ablation dispatches (scratch sync regions; rings are overwritten-before-read
  // by the real pass, and kernel-boundary invalidation is r12-r14-proven).
  {
    sp.bar = bar + 0 * 1024;
    void* kp[1] = {&sp};
    hipLaunchCooperativeKernel(reinterpret_cast<void*>(&k_scan<0>),
                               dim3(256), dim3(256), kp, 0, stream);
  }
  {
    sp.bar = bar + 1 * 1024;
    void* kp[1] = {&sp};
    hipLaunchCooperativeKernel(reinterpret_cast<void*>(&k_scan<1>),
                               dim3(256), dim3(256), kp, 0, stream);
  }
  {
    sp.bar = bar + 2 * 1024;
    void* kp[1] = {&sp};
    hipLaunchCooperativeKernel(reinterpret_cast<void*>(&k_scan<2>),
                               dim3(256), dim3(256), kp, 0, stream);
  }
  // Real pass (last): produces d_out.
  {
    sp.bar = bar + 3 * 1024;
    void* kp[1] = {&sp};
    hipLaunchCooperativeKernel(reinterpret_cast<void*>(&k_scan<3>),
                               dim3(256), dim3(256), kp, 0, stream);
  }
}

// Round 17
// 7149.411 us; speedup vs baseline: 2.3521x; 2.3521x over previous
//
#include <hip/hip_runtime.h>
#include <hip/hip_bf16.h>
#include <stdint.h>

#define T_STEPS 512
#define NBATCH 64
#define HID 1024
#define NGATE 4096
#define NLAYERS 2
#define BH (NBATCH * HID)            // 65536
#define TBH (T_STEPS * NBATCH * HID) // 33554432
#define WEL ((size_t)NLAYERS * NGATE * HID)
#define GBLK 128                     // blocks per barrier group

typedef __attribute__((ext_vector_type(8))) short short8;
typedef __attribute__((ext_vector_type(4))) float f32x4;

__device__ __forceinline__ ushort f2bf(float f) {
  union { float f; uint32_t i; } u; u.f = f;
  return (ushort)((u.i + 0x7fffu + ((u.i >> 16) & 1u)) >> 16);  // RNE
}
__device__ __forceinline__ void gll16(const void* g, void* l) {
  __builtin_amdgcn_global_load_lds(
      (const __attribute__((address_space(1))) unsigned int*)g,
      (__attribute__((address_space(3))) unsigned int*)l, 16, 0, 0);
}

// ---- A-load pipe: 16 rotating slots, counted vmcnt (r7-proven), cached loads.
#define ISSC(S, P, OFF) \
  asm volatile("global_load_dwordx4 %0, %1, off offset:" #OFF \
               : "=v"(fr[S]) : "v"(P));
#define VMW(N, SLOT) \
  asm volatile("s_waitcnt vmcnt(" #N ")" : "+v"(fr[SLOT]));
#define CON(SLOT, KC) { \
    const short8 b0v = *(const short8*)(bb0 + ((((KC) * 64) + kb) ^ bsw)); \
    const short8 b1v = *(const short8*)(bb1 + ((((KC) * 64) + kb) ^ bsw)); \
    accA = __builtin_amdgcn_mfma_f32_16x16x32_bf16(fr[SLOT], b0v, accA, 0, 0, 0); \
    accB = __builtin_amdgcn_mfma_f32_16x16x32_bf16(fr[SLOT], b1v, accB, 0, 0, 0); }

// One K=1024 half (r13-proven): issue 16, interleave, countdown to 0.
#define PIPE32(Pp, KB) \
  ISSC(0,Pp,0)    ISSC(1,Pp,64)   ISSC(2,Pp,128)  ISSC(3,Pp,192)  \
  ISSC(4,Pp,256)  ISSC(5,Pp,320)  ISSC(6,Pp,384)  ISSC(7,Pp,448)  \
  ISSC(8,Pp,512)  ISSC(9,Pp,576)  ISSC(10,Pp,640) ISSC(11,Pp,704) \
  ISSC(12,Pp,768) ISSC(13,Pp,832) ISSC(14,Pp,896) ISSC(15,Pp,960) \
  VMW(15,0)  CON(0,(KB)+0)   ISSC(0,Pp,1024)  \
  VMW(15,1)  CON(1,(KB)+1)   ISSC(1,Pp,1088)  \
  VMW(15,2)  CON(2,(KB)+2)   ISSC(2,Pp,1152)  \
  VMW(15,3)  CON(3,(KB)+3)   ISSC(3,Pp,1216)  \
  VMW(15,4)  CON(4,(KB)+4)   ISSC(4,Pp,1280)  \
  VMW(15,5)  CON(5,(KB)+5)   ISSC(5,Pp,1344)  \
  VMW(15,6)  CON(6,(KB)+6)   ISSC(6,Pp,1408)  \
  VMW(15,7)  CON(7,(KB)+7)   ISSC(7,Pp,1472)  \
  VMW(15,8)  CON(8,(KB)+8)   ISSC(8,Pp,1536)  \
  VMW(15,9)  CON(9,(KB)+9)   ISSC(9,Pp,1600)  \
  VMW(15,10) CON(10,(KB)+10) ISSC(10,Pp,1664) \
  VMW(15,11) CON(11,(KB)+11) ISSC(11,Pp,1728) \
  VMW(15,12) CON(12,(KB)+12) ISSC(12,Pp,1792) \
  VMW(15,13) CON(13,(KB)+13) ISSC(13,Pp,1856) \
  VMW(15,14) CON(14,(KB)+14) ISSC(14,Pp,1920) \
  VMW(15,15) CON(15,(KB)+15) ISSC(15,Pp,1984) \
  VMW(15,0)  CON(0,(KB)+16)  \
  VMW(14,1)  CON(1,(KB)+17)  \
  VMW(13,2)  CON(2,(KB)+18)  \
  VMW(12,3)  CON(3,(KB)+19)  \
  VMW(11,4)  CON(4,(KB)+20)  \
  VMW(10,5)  CON(5,(KB)+21)  \
  VMW(9,6)   CON(6,(KB)+22)  \
  VMW(8,7)   CON(7,(KB)+23)  \
  VMW(7,8)   CON(8,(KB)+24)  \
  VMW(6,9)   CON(9,(KB)+25)  \
  VMW(5,10)  CON(10,(KB)+26) \
  VMW(4,11)  CON(11,(KB)+27) \
  VMW(3,12)  CON(12,(KB)+28) \
  VMW(2,13)  CON(13,(KB)+29) \
  VMW(1,14)  CON(14,(KB)+30) \
  VMW(0,15)  CON(15,(KB)+31)

// L2 prefetch of next step's self-slice: 32 dead-dest loads (values never read,
// no live state -> no r15 spill hazard). Issued after the load-back sink; they
// drain under garrive's syncthreads. Converts next step's L2 misses into hits
// (r16 ablation: A-load pipe = 8.6us/step of the 10.9, dominated by miss rate).
#define PF32(Pp) \
  ISSC(0,Pp,0)     ISSC(1,Pp,64)    ISSC(2,Pp,128)   ISSC(3,Pp,192)  \
  ISSC(4,Pp,256)   ISSC(5,Pp,320)   ISSC(6,Pp,384)   ISSC(7,Pp,448)  \
  ISSC(8,Pp,512)   ISSC(9,Pp,576)   ISSC(10,Pp,640)  ISSC(11,Pp,704) \
  ISSC(12,Pp,768)  ISSC(13,Pp,832)  ISSC(14,Pp,896)  ISSC(15,Pp,960) \
  ISSC(0,Pp,1024)  ISSC(1,Pp,1088)  ISSC(2,Pp,1152)  ISSC(3,Pp,1216) \
  ISSC(4,Pp,1280)  ISSC(5,Pp,1344)  ISSC(6,Pp,1408)  ISSC(7,Pp,1472) \
  ISSC(8,Pp,1536)  ISSC(9,Pp,1600)  ISSC(10,Pp,1664) ISSC(11,Pp,1728)\
  ISSC(12,Pp,1792) ISSC(13,Pp,1856) ISSC(14,Pp,1920) ISSC(15,Pp,1984)

// ---------------- elementwise helpers ----------------
__global__ void k_f32_to_bf16(const float* __restrict__ in, ushort* __restrict__ out, int n) {
  int i = (blockIdx.x * blockDim.x + threadIdx.x) * 4;
  if (i >= n) return;
  const float4 v = *reinterpret_cast<const float4*>(in + i);
  ushort4 o; o.x = f2bf(v.x); o.y = f2bf(v.y); o.z = f2bf(v.z); o.w = f2bf(v.w);
  *reinterpret_cast<ushort4*>(out + i) = o;
}
__global__ void k_zero(int* p, int n) {
  int i = blockIdx.x * blockDim.x + threadIdx.x;
  if (i < n) p[i] = 0;
}

// ---------------- persistent fused scan (r13 structure + prefetch) ----------------
struct ScanP {
  const ushort* wih; const ushort* whh;
  const ushort* xb;  const ushort* hinit;
  ushort* h0r;                            // layer-0 h ring (T_STEPS slots)
  ushort* h1r;                            // layer-1 h ring (T_STEPS slots)
  const float* c0; const float* bi; const float* bh;
  float* out; int* bar;
};

__device__ __forceinline__ void garrive(int* gb, int stripe) {
  __syncthreads();  // drains vmcnt: stores, load-back, prefetches
  if (threadIdx.x == 0)
    __hip_atomic_fetch_add(gb + stripe * 16, 1, __ATOMIC_RELAXED, __HIP_MEMORY_SCOPE_AGENT);
}
__device__ __forceinline__ void gwait(int* gb, int target, bool isRoot) {
  if (threadIdx.x == 0) {
    if (isRoot) {
      const int need = target * GBLK;
      for (;;) {
        int sum = 0;
#pragma unroll
        for (int i = 0; i < 16; ++i)
          sum += __hip_atomic_load(gb + i * 16, __ATOMIC_RELAXED, __HIP_MEMORY_SCOPE_AGENT);
        if (sum >= need) break;
        __builtin_amdgcn_s_sleep(1);
      }
      __hip_atomic_store(gb + 256, target, __ATOMIC_RELAXED, __HIP_MEMORY_SCOPE_AGENT);
    } else {
      while (__hip_atomic_load(gb + 256, __ATOMIC_RELAXED, __HIP_MEMORY_SCOPE_AGENT) < target)
        __builtin_amdgcn_s_sleep(2);
    }
  }
  __syncthreads();
  __builtin_amdgcn_sched_barrier(0);
}

// 256 blocks x 256 threads. Group 0 = layer 0 (sprints ahead); group 1 = layer 1
// (one-way gated on rel0). Per step: EARLY half (prefetched last step -> L2-hit),
// own-group wait, LATE half, epilogue, h-store+load-back, PREFETCH next EARLY.
__global__ __launch_bounds__(256, 1) void k_scan(ScanP p) {
  __shared__ __align__(16) ushort Wl[32 * 2048];  // 128 KB
  __shared__ float glds[64 * 33];
  __shared__ int pfsh;
  const int tid = threadIdx.x, wave = tid >> 6, lane = tid & 63;
  const bool isL1 = blockIdx.x >= 128;
  const int cb = isL1 ? (int)blockIdx.x - 128 : (int)blockIdx.x;
  const int j0 = cb * 8;
  const int stripe = cb & 15;
  const bool isRoot = (cb == 0);
  int* gb = p.bar + (isL1 ? 512 : 0);
  const int* rel0 = p.bar + 256;

  const ushort* wihL = p.wih + (isL1 ? (size_t)NGATE * HID : 0);
  const ushort* whhL = p.whh + (isL1 ? (size_t)NGATE * HID : 0);
  for (int q = wave; q < 128; q += 4) {
    const int i = q >> 2, ch = q & 3;
    const ushort* base = (ch < 2) ? wihL : whhL;
    const int g = (i >> 3) * 1024 + j0 + (i & 7);
    gll16(base + (size_t)g * 1024 + (ch & 1) * 512 + (((lane * 16) ^ ((i & 7) << 4)) >> 1),
          (char*)Wl + i * 4096 + ch * 1024);
  }

  const int eb  = tid >> 2;
  const int jl0 = (tid & 3) * 2;
  const int jj  = j0 + jl0;
  const int lofs = isL1 ? NGATE : 0;
  float creg[2], bias[4][2];
#pragma unroll
  for (int i = 0; i < 2; ++i) creg[i] = p.c0[(isL1 ? BH : 0) + eb * 1024 + jj + i];
#pragma unroll
  for (int g = 0; g < 4; ++g)
#pragma unroll
    for (int i = 0; i < 2; ++i)
      bias[g][i] = p.bi[lofs + g * 1024 + jj + i] + p.bh[lofs + g * 1024 + jj + i];

  const size_t aoff = (size_t)(wave * 16 + (lane & 15)) * 1024 + (size_t)((lane >> 4) * 8);
  const int r0 = lane & 15;
  const char* bb0 = (const char*)Wl + r0 * 4096;
  const char* bb1 = (const char*)Wl + (r0 + 16) * 4096;
  const int bsw = (r0 & 7) << 4;
  const int kb = (lane >> 4) * 16;

  int seen0 = 0;  // L1: cached rel0 watermark (thread 0 only)

  __syncthreads();  // W staged

  for (int t = 0; t < T_STEPS; ++t) {
    f32x4 accA = {0.f, 0.f, 0.f, 0.f}, accB = {0.f, 0.f, 0.f, 0.f};
    short8 fr[16];
    bool pfOK = false;

    if (!isL1) {
      { const ushort* Pp = p.xb + (size_t)t * BH + aoff;          // EARLY: x_t (prefetched)
        PIPE32(Pp, 0) }
      if (t > 0) gwait(gb, t, isRoot);                            // own group t-1 done
      { const ushort* Qp = ((t == 0) ? p.hinit
                                     : p.h0r + (size_t)(t - 1) * BH) + aoff;
        PIPE32(Qp, 32) }                                          // LATE: h0[t-1]
    } else {
      if (threadIdx.x == 0) {                                     // gate: h0[t]
        if (seen0 < t + 1) {
          int v = __hip_atomic_load(rel0, __ATOMIC_RELAXED, __HIP_MEMORY_SCOPE_AGENT);
          while (v < t + 1) {
            __builtin_amdgcn_s_sleep(2);
            v = __hip_atomic_load(rel0, __ATOMIC_RELAXED, __HIP_MEMORY_SCOPE_AGENT);
          }
          seen0 = v;
        }
        pfsh = (seen0 >= t + 2) ? 1 : 0;  // h0[t+1] fully committed already?
      }
      __syncthreads();
      __builtin_amdgcn_sched_barrier(0);
      pfOK = (pfsh != 0);
      { const ushort* Pp = p.h0r + (size_t)t * BH + aoff;         // EARLY: h0[t] (prefetched)
        PIPE32(Pp, 0) }
      if (t > 0) gwait(gb, t, isRoot);                            // own group t-1 done
      { const ushort* Qp = ((t == 0) ? p.hinit + BH
                                     : p.h1r + (size_t)(t - 1) * BH) + aoff;
        PIPE32(Qp, 32) }                                          // LATE: h1[t-1]
    }

#pragma unroll
    for (int r = 0; r < 4; ++r) {
      const int row = wave * 16 + (lane >> 4) * 4 + r;
      glds[row * 33 + r0]      = accA[r];
      glds[row * 33 + 16 + r0] = accB[r];
    }
    __syncthreads();

    float hres[2];
#pragma unroll
    for (int i = 0; i < 2; ++i) {
      const int jl = jl0 + i;
      const float gi = glds[eb * 33 + jl]      + bias[0][i];
      const float gf = glds[eb * 33 + 8 + jl]  + bias[1][i];
      const float gg = glds[eb * 33 + 16 + jl] + bias[2][i];
      const float go = glds[eb * 33 + 24 + jl] + bias[3][i];
      float c = creg[i];
      const float si = 1.f / (1.f + __expf(-gi));
      const float sf = 1.f / (1.f + __expf(-gf));
      const float so = 1.f / (1.f + __expf(-go));
      const float tg = tanhf(gg);
      c = sf * c + si * tg;
      hres[i] = so * tanhf(c);
      creg[i] = c;
    }

    const uint32_t packed = (uint32_t)f2bf(hres[0]) | ((uint32_t)f2bf(hres[1]) << 16);
    ushort* hdst = (!isL1) ? (p.h0r + (size_t)t * BH) : (p.h1r + (size_t)t * BH);
    uint32_t* hw = (uint32_t*)(hdst + eb * 1024 + jj);
    __hip_atomic_store(hw, packed, __ATOMIC_RELAXED, __HIP_MEMORY_SCOPE_AGENT);
    // same-address load-back: store committed at coherence point before arrive
    uint32_t chk = __hip_atomic_load(hw, __ATOMIC_RELAXED, __HIP_MEMORY_SCOPE_AGENT);
    asm volatile("" :: "v"(chk));

    if (isL1) {
#pragma unroll
      for (int i = 0; i < 2; ++i)
        p.out[(size_t)t * BH + eb * 1024 + jj + i] = hres[i];
      if (t == T_STEPS - 1) {
#pragma unroll
        for (int i = 0; i < 2; ++i) {
          p.out[(size_t)TBH + BH + eb * 1024 + jj + i] = hres[i];
          p.out[(size_t)TBH + 3 * BH + eb * 1024 + jj + i] = creg[i];
        }
      }
    } else if (t == T_STEPS - 1) {
#pragma unroll
      for (int i = 0; i < 2; ++i) {
        p.out[(size_t)TBH + eb * 1024 + jj + i] = hres[i];
        p.out[(size_t)TBH + 2 * BH + eb * 1024 + jj + i] = creg[i];
      }
    }

    // ---- L2 self-slice prefetch of next step's EARLY half (drains at garrive) ----
    if (!isL1) {
      if (t + 1 < T_STEPS) { const ushort* Pn = p.xb + (size_t)(t + 1) * BH + aoff; PF32(Pn) }
    } else {
      if (pfOK && t + 1 < T_STEPS) { const ushort* Pn = p.h0r + (size_t)(t + 1) * BH + aoff; PF32(Pn) }
    }

    garrive(gb, stripe);
  }

  // tail publisher: L1 steps 510/511 need rel0 beyond the in-loop publish.
  if (!isL1 && isRoot && threadIdx.x == 0) {
    const int need = T_STEPS * GBLK;
    for (;;) {
      int sum = 0;
#pragma unroll
      for (int i = 0; i < 16; ++i)
        sum += __hip_atomic_load(gb + i * 16, __ATOMIC_RELAXED, __HIP_MEMORY_SCOPE_AGENT);
      if (sum >= need) break;
      __builtin_amdgcn_s_sleep(1);
    }
    __hip_atomic_store(gb + 256, T_STEPS + 1, __ATOMIC_RELAXED, __HIP_MEMORY_SCOPE_AGENT);
  }
}

// ---------------- host ----------------
extern "C" void kernel_launch(void* const* d_in, const int* in_sizes, int n_in,
                              void* d_out, int out_size, void* d_ws, size_t ws_size,
                              hipStream_t stream) {
  const float* x    = (const float*)d_in[0];
  const float* h0   = (const float*)d_in[1];
  const float* c0   = (const float*)d_in[2];
  const float* w_ih = (const float*)d_in[3];
  const float* w_hh = (const float*)d_in[4];
  const float* b_ih = (const float*)d_in[5];
  const float* b_hh = (const float*)d_in[6];
  float* out = (float*)d_out;

  ushort* xb    = (ushort*)d_ws;
  ushort* wihb  = xb + (size_t)TBH;
  ushort* whhb  = wihb + WEL;
  ushort* hinit = whhb + WEL;
  ushort* h0r   = hinit + 2 * (size_t)BH;            // ring: T_STEPS slots
  ushort* h1r   = h0r + (size_t)TBH;                 // ring: T_STEPS slots
  int*    bar   = (int*)(h1r + (size_t)TBH);

  const size_t need = ((size_t)3 * TBH + 2 * WEL + 2 * (size_t)BH) * 2 + 4096;
  if (ws_size < need) return;  // loud failure: d_out stays poisoned

  { int n = TBH;        k_f32_to_bf16<<<(n / 4 + 255) / 256, 256, 0, stream>>>(x, xb, n); }
  { int n = (int)WEL;   k_f32_to_bf16<<<(n / 4 + 255) / 256, 256, 0, stream>>>(w_ih, wihb, n); }
  { int n = (int)WEL;   k_f32_to_bf16<<<(n / 4 + 255) / 256, 256, 0, stream>>>(w_hh, whhb, n); }
  { int n = 2 * BH;     k_f32_to_bf16<<<(n / 4 + 255) / 256, 256, 0, stream>>>(h0, hinit, n); }
  k_zero<<<4, 256, 0, stream>>>(bar, 1024);

  ScanP sp;
  sp.wih = wihb; sp.whh = whhb;
  sp.xb = xb; sp.hinit = hinit;
  sp.h0r = h0r; sp.h1r = h1r;
  sp.c0 = c0; sp.bi = b_ih; sp.bh = b_hh;
  sp.out = out; sp.bar = bar;

  void* kp[1] = {&sp};
  hipLaunchCooperativeKernel(reinterpret_cast<void*>(&k_scan),
                             dim3(256), dim3(256), kp, 0, stream);
}